// Round 13
// baseline (45.980 us; speedup 1.0000x reference)
//
#include <hip/hip_runtime.h>
#include <hip/hip_fp16.h>
#include <stdint.h>

// Problem constants (B, L, C, H, W) = (2, 48, 8, 48, 48)
constexpr int B = 2, L = 48, C = 8, H = 48, W = 48;
constexpr int HW = H * W;   // 2304

constexpr int TPB    = 256;        // threads per block (= pixels per chunk)
constexpr int CHUNKS = HW / TPB;   // 9

constexpr int OUT_ELEMS = B * L * C * HW;             // 1,769,472

constexpr int NCUM        = B * 2 * HW;               // 9216 cumsum threads
constexpr int CUM_BLOCKS  = NCUM / 256;               // 36
constexpr int NCONV       = B * L * HW;               // 221184 convert threads
constexpr int CONV_BLOCKS = (NCONV + 255) / 256;      // 864

// ---------------------------------------------------------------------------
// Prep kernel (unchanged): cumsum of flows -> cum2 (B,L,HW,2) fp32 (same
// accumulation order as jnp.cumsum); images -> fp16 channel-last imgH.
// ---------------------------------------------------------------------------
__global__ void prep_kernel(const float* __restrict__ flows,
                            const float* __restrict__ images,
                            float* __restrict__ cum2,
                            __half* __restrict__ imgH) {
    if (blockIdx.x < CUM_BLOCKS) {
        int tid  = blockIdx.x * 256 + threadIdx.x;     // < NCUM
        int pix  = tid % HW;
        int comp = (tid / HW) & 1;
        int b    = tid / (2 * HW);
        const float* src = flows + (size_t)b * L * 2 * HW + (size_t)comp * HW + pix;
        float*       dst = cum2  + ((size_t)b * L * HW + pix) * 2 + comp;
        float acc = 0.0f;
#pragma unroll
        for (int l = 0; l < L; ++l) {
            acc += src[(size_t)l * 2 * HW];
            dst[(size_t)l * HW * 2] = acc;
        }
    } else {
        int tid = (blockIdx.x - CUM_BLOCKS) * 256 + threadIdx.x;
        if (tid >= NCONV) return;
        int pix = tid % HW;
        int bl  = tid / HW;
        const float* src = images + (size_t)bl * C * HW + pix;
        __half h[C];
#pragma unroll
        for (int c = 0; c < C; ++c) h[c] = __float2half(src[(size_t)c * HW]);
        float4* dst = reinterpret_cast<float4*>(imgH + ((size_t)bl * HW + pix) * C);
        *dst = *reinterpret_cast<float4*>(h);
    }
}

// ---------------------------------------------------------------------------
// Per-sample geometry (lean, R12-proven).
// x wrap: remainder(v,2) = v - 2*floor(v*0.5) — bit-identical to the
// reference's jnp.remainder for our value range (intermediates exact,
// same single final rounding op). Validity (UNCLAMPED floored coords,
// matching the reference) folded into wx/wy before the weight products.
// x0f in [-1,47] automatically (v in [0,2)); y0f UNBOUNDED -> double-sided
// clamps (one-sided clamping caused R5's 0*NaN poisoning — never again).
// ---------------------------------------------------------------------------
struct TapPack {
    float w00, w10, w01, w11;
    int o00, o10, o01, o11;    // element offsets of the 4 clamped taps
};

__device__ __forceinline__ TapPack geom(float base_gx_p1, float base_gy,
                                        float relx, float rely) {
    float v = base_gx_p1 + relx;
    v = __builtin_fmaf(-2.0f, floorf(v * 0.5f), v);       // remainder(v,2) in [0,2)

    float ix = __builtin_fmaf(v, 24.0f, -0.5f);           // [-0.5, 47.5)
    float gy = base_gy + rely;
    float iy = __builtin_fmaf(gy, 24.0f, 23.5f);

    float x0f = floorf(ix), y0f = floorf(iy);
    float wx1 = ix - x0f,   wy1 = iy - y0f;
    float wx0 = 1.0f - wx1, wy0 = 1.0f - wy1;

    // validity folded (x0f <= 47 and x0f >= -1 hold automatically)
    wx0 = (x0f >= 0.0f)                      ? wx0 : 0.0f;
    wx1 = (x0f <= 46.0f)                     ? wx1 : 0.0f;
    wy0 = (y0f >= 0.0f  && y0f <= 47.0f)     ? wy0 : 0.0f;
    wy1 = (y0f >= -1.0f && y0f <= 46.0f)     ? wy1 : 0.0f;

    // clamped integer taps (y unbounded -> double-sided; x1 clamp needed so
    // the b128 LDS read can't run off the frame into NaN-capable bits)
    int x0 = (int)fmaxf(x0f, 0.0f);
    int x1 = (int)fminf(x0f + 1.0f, 47.0f);
    int y0 = (int)fminf(fmaxf(y0f,        0.0f), 47.0f);
    int y1 = (int)fminf(fmaxf(y0f + 1.0f, 0.0f), 47.0f);

    TapPack t;
    t.w00 = wx0 * wy0; t.w10 = wx1 * wy0;
    t.w01 = wx0 * wy1; t.w11 = wx1 * wy1;
    int y0b = y0 * (W * C), y1b = y1 * (W * C);
    t.o00 = y0b + x0 * C;  t.o10 = y0b + x1 * C;
    t.o01 = y1b + x0 * C;  t.o11 = y1b + x1 * C;
    return t;
}

// ---------------------------------------------------------------------------
// f32 += f16 * f32 via v_fma_mix_f32 (no separate cvt): lo and hi half of
// one 32-bit word of packed f16 into two accumulators.
// ---------------------------------------------------------------------------
__device__ __forceinline__ void fma_mix2(float& alo, float& ahi, uint32_t hw, float w) {
    asm("v_fma_mix_f32 %0, %2, %3, %0 op_sel:[0,0,0] op_sel_hi:[1,0,0]\n\t"
        "v_fma_mix_f32 %1, %2, %3, %1 op_sel:[1,0,0] op_sel_hi:[1,0,0]"
        : "+v"(alo), "+v"(ahi)
        : "v"(hw), "v"(w));
}

// ---------------------------------------------------------------------------
// Stage one fp16 frame (2304 records x 16B = 36.9 KB) global -> LDS, linear.
// ---------------------------------------------------------------------------
#if defined(__has_builtin)
#if __has_builtin(__builtin_amdgcn_global_load_lds)
#define HAVE_GLD_LDS 1
#endif
#endif

__device__ __forceinline__ void stage_frame(const __half* __restrict__ gsrc,
                                            __half* lds_base, int tid) {
#ifdef HAVE_GLD_LDS
#pragma unroll
    for (int i = 0; i < 9; ++i) {
        const int r = i * 256 + tid;
        __builtin_amdgcn_global_load_lds(
            (const __attribute__((address_space(1))) void*)(gsrc + (size_t)r * C),
            (__attribute__((address_space(3))) void*)(lds_base + (size_t)r * C),
            16, 0, 0);
    }
#else
#pragma unroll
    for (int i = 0; i < 9; ++i) {
        const int r = i * 256 + tid;
        float4 v = *reinterpret_cast<const float4*>(gsrc + (size_t)r * C);
        *reinterpret_cast<float4*>(lds_base + (size_t)r * C) = v;
    }
#endif
}

// ---------------------------------------------------------------------------
// Gather 4 taps from the LDS frame, accumulate 8 channels via fma_mix.
// Clamped offsets + zeroed weights (0 * finite LDS data — no NaN possible).
// ---------------------------------------------------------------------------
__device__ __forceinline__ void gather_mix(const __half* fb, const TapPack& t,
                                           float acc[C]) {
    float4 r00 = *reinterpret_cast<const float4*>(fb + t.o00);
    float4 r10 = *reinterpret_cast<const float4*>(fb + t.o10);
    float4 r01 = *reinterpret_cast<const float4*>(fb + t.o01);
    float4 r11 = *reinterpret_cast<const float4*>(fb + t.o11);
    auto mixtap = [&](const float4& raw, float w) {
        const uint32_t* u = reinterpret_cast<const uint32_t*>(&raw);
        fma_mix2(acc[0], acc[1], u[0], w);
        fma_mix2(acc[2], acc[3], u[1], w);
        fma_mix2(acc[4], acc[5], u[2], w);
        fma_mix2(acc[6], acc[7], u[3], w);
    };
    mixtap(r00, t.w00); mixtap(r10, t.w10);
    mixtap(r01, t.w01); mixtap(r11, t.w11);
}

// ---------------------------------------------------------------------------
// Main kernel: T=16 t's per staged frame, k split into P=8 parity classes.
// Proven R7/R10/R12 loop shape: double-buffered global_load_lds staging, one
// barrier per k, 73.7 KB LDS -> 2 blocks/CU (co-resident blocks hide each
// other's barrier drains). Staging total = CHUNKS*NG*96 = 9*3*96 = 2592
// frame-stages (-25% vs R12's 3456) — staging volume is the measured wall.
// t-set(g) = {6m+g, 6m+5-g}, m=0..7, g in 0..2: uniform 392 samples/pixel,
// kmax = 47-g. Block = (chunk, g, par + P*b); grid (9,3,16) = 432 blocks.
// acc[16][8] = 128 VGPR; lean TapPack keeps total ~205 < 256 cap
// (launch_bounds(256,2)). R11's T16 regression was the FAT geometry spilling;
// this is the retry with the diet in place.
// par==0 writes out (fp32); par p>0 writes fp16 partial p-1; reduce sums.
// ---------------------------------------------------------------------------
constexpr int TT = 16;
constexpr int P  = 8;

__global__ __launch_bounds__(256, 2) void scan_kernel(const float* __restrict__ cum2,
                                                      const __half* __restrict__ imgH,
                                                      float* __restrict__ out,
                                                      __half* __restrict__ part) {
    const int tid  = threadIdx.x;
    const int pix0 = blockIdx.x * TPB;
    const int pix  = pix0 + tid;
    const int g    = blockIdx.y;
    const int par  = blockIdx.z % P;
    const int b    = blockIdx.z / P;

    int tj[TT];
#pragma unroll
    for (int m = 0; m < TT / 2; ++m) {
        tj[2 * m]     = 6 * m + g;
        tj[2 * m + 1] = 6 * m + 5 - g;
    }
    const int kmax = 47 - g;

    const int w = pix % W;
    const int h = pix / W;
    const float base_gx_p1 = (2 * w + 1) * (1.0f / W);
    const float base_gy    = (2 * h + 1) * (1.0f / H) - 1.0f;

    const float* cb = cum2 + ((size_t)b * L * HW + pix) * 2;
    float ctx[TT], cty[TT];
#pragma unroll
    for (int j = 0; j < TT; ++j) {
        float2 c = *reinterpret_cast<const float2*>(cb + (size_t)tj[j] * HW * 2);
        ctx[j] = c.x; cty[j] = c.y;
    }

    float acc[TT][C];
#pragma unroll
    for (int j = 0; j < TT; ++j)
#pragma unroll
        for (int c = 0; c < C; ++c) acc[j][c] = 0.0f;

    // 73.7 KB: two fp16 frame buffers (epilogue reuses as fp32 [64][256])
    __shared__ __align__(16) unsigned char smem[2 * HW * C * 2];
    __half* fr0 = reinterpret_cast<__half*>(smem);
    __half* fr1 = reinterpret_cast<__half*>(smem + HW * C * 2);

    const __half* gb = imgH + (size_t)b * L * HW * C;

    stage_frame(gb + (size_t)par * HW * C, fr0, tid);       // frame k=par
    float2 ck = *reinterpret_cast<const float2*>(cb + (size_t)par * HW * 2);
    __syncthreads();                                        // staging visible

    int cur = 0;
    for (int k = par; k <= kmax; k += P) {
        __half* nb = cur ? fr0 : fr1;
        const __half* fb = cur ? fr1 : fr0;
        if (k + P <= kmax)
            stage_frame(gb + (size_t)(k + P) * HW * C, nb, tid);
        float2 ckn = ck;
        if (k + P <= kmax)
            ckn = *reinterpret_cast<const float2*>(cb + (size_t)(k + P) * HW * 2);

#pragma unroll
        for (int j = 0; j < TT; ++j) {
            if (tj[j] >= k) {   // block-uniform guard
                TapPack t = geom(base_gx_p1, base_gy, ctx[j] - ck.x, cty[j] - ck.y);
                gather_mix(fb, t, acc[j]);
            }
        }

        ck = ckn;
        __syncthreads();    // gathers done + next staging landed -> safe swap
        cur ^= 1;
    }

    // ---- epilogue: transpose acc through LDS, 2 rounds of 64 planes ----
    float* accT = reinterpret_cast<float*>(smem);       // [64][256] = 64 KB
    const int lane = tid & 63;
    const int wv   = tid >> 6;

#pragma unroll
    for (int rd = 0; rd < 2; ++rd) {
        __syncthreads();
#pragma unroll
        for (int j = 0; j < TT; ++j)
#pragma unroll
            for (int c = 0; c < C; ++c) {
                int pl = j * C + c;
                if ((pl >> 6) == rd)
                    accT[(pl & 63) * TPB + tid] = acc[j][c];
            }
        __syncthreads();

#pragma unroll
        for (int rr = 0; rr < 16; ++rr) {               // 64 planes / 4 waves
            int pl_l = wv + 4 * rr;
            int pl_g = rd * 64 + pl_l;
            int j = pl_g >> 3, c = pl_g & 7;
            float4 v = *reinterpret_cast<float4*>(&accT[pl_l * TPB + lane * 4]);
            size_t off = ((size_t)(b * L + tj[j]) * C + c) * HW + pix0 + lane * 4;
            if (par == 0) {
                *reinterpret_cast<float4*>(out + off) = v;
            } else {
                __half hb[4];
                hb[0] = __float2half(v.x); hb[1] = __float2half(v.y);
                hb[2] = __float2half(v.z); hb[3] = __float2half(v.w);
                *reinterpret_cast<float2*>(part + (size_t)(par - 1) * OUT_ELEMS + off) =
                    *reinterpret_cast<float2*>(hb);
            }
        }
    }
}

// ---------------------------------------------------------------------------
// Reduce: out += sum of NPART fp16 partials, fixed order -> deterministic.
// ---------------------------------------------------------------------------
template <int NPART>
__global__ void reduce_kernel(float* __restrict__ out, const __half* __restrict__ part) {
    int i = blockIdx.x * blockDim.x + threadIdx.x;
    constexpr int N4 = OUT_ELEMS / 4;
    if (i < N4) {
        float4 a = reinterpret_cast<float4*>(out)[i];
#pragma unroll
        for (int p = 0; p < NPART; ++p) {
            const __half2* hp = reinterpret_cast<const __half2*>(
                part + (size_t)p * OUT_ELEMS + 4 * (size_t)i);
            float2 f01 = __half22float2(hp[0]);
            float2 f23 = __half22float2(hp[1]);
            a.x += f01.x; a.y += f01.y; a.z += f23.x; a.w += f23.y;
        }
        reinterpret_cast<float4*>(out)[i] = a;
    }
}

// ---------------------------------------------------------------------------
extern "C" void kernel_launch(void* const* d_in, const int* in_sizes, int n_in,
                              void* d_out, int out_size, void* d_ws, size_t ws_size,
                              hipStream_t stream) {
    const float* flows  = (const float*)d_in[0];   // (B, L, 2, H, W) fp32
    const float* images = (const float*)d_in[1];   // (B, L, C, H, W) fp32
    float* out = (float*)d_out;                    // (B, L, C, H, W) fp32

    const size_t cum_elems  = (size_t)B * L * 2 * HW;     // 442,368 f32
    const size_t imgH_elems = (size_t)B * L * HW * C;     // 1,769,472 f16

    float*  cum2 = (float*)d_ws;
    __half* imgH = (__half*)(cum2 + cum_elems);
    __half* part = imgH + imgH_elems;                     // 7 fp16 partials (24.8 MB)

    prep_kernel<<<CUM_BLOCKS + CONV_BLOCKS, 256, 0, stream>>>(flows, images, cum2, imgH);

    dim3 grid(CHUNKS, 3, 2 * P);                          // (9, 3, 16) = 432 blocks
    scan_kernel<<<grid, 256, 0, stream>>>(cum2, imgH, out, part);

    constexpr int N4 = OUT_ELEMS / 4;
    reduce_kernel<P - 1><<<(N4 + 255) / 256, 256, 0, stream>>>(out, part);
}

// Round 14
// 42.368 us; speedup vs baseline: 1.0853x; 1.0853x over previous
//
#include <hip/hip_runtime.h>
#include <hip/hip_fp16.h>
#include <stdint.h>

// Problem constants (B, L, C, H, W) = (2, 48, 8, 48, 48)
constexpr int B = 2, L = 48, C = 8, H = 48, W = 48;
constexpr int HW = H * W;   // 2304

constexpr int TPB    = 256;        // threads per block (= pixels per chunk)
constexpr int CHUNKS = HW / TPB;   // 9

constexpr int OUT_ELEMS = B * L * C * HW;             // 1,769,472

constexpr int NCUM        = B * 2 * HW;               // 9216 cumsum threads
constexpr int CUM_BLOCKS  = NCUM / 256;               // 36
constexpr int NCONV       = B * L * HW;               // 221184 convert threads
constexpr int CONV_BLOCKS = (NCONV + 255) / 256;      // 864

// ---------------------------------------------------------------------------
// Prep kernel (unchanged): cumsum of flows -> cum2 (B,L,HW,2) fp32 (same
// accumulation order as jnp.cumsum); images -> fp16 channel-last imgH.
// ---------------------------------------------------------------------------
__global__ void prep_kernel(const float* __restrict__ flows,
                            const float* __restrict__ images,
                            float* __restrict__ cum2,
                            __half* __restrict__ imgH) {
    if (blockIdx.x < CUM_BLOCKS) {
        int tid  = blockIdx.x * 256 + threadIdx.x;     // < NCUM
        int pix  = tid % HW;
        int comp = (tid / HW) & 1;
        int b    = tid / (2 * HW);
        const float* src = flows + (size_t)b * L * 2 * HW + (size_t)comp * HW + pix;
        float*       dst = cum2  + ((size_t)b * L * HW + pix) * 2 + comp;
        float acc = 0.0f;
#pragma unroll
        for (int l = 0; l < L; ++l) {
            acc += src[(size_t)l * 2 * HW];
            dst[(size_t)l * HW * 2] = acc;
        }
    } else {
        int tid = (blockIdx.x - CUM_BLOCKS) * 256 + threadIdx.x;
        if (tid >= NCONV) return;
        int pix = tid % HW;
        int bl  = tid / HW;
        const float* src = images + (size_t)bl * C * HW + pix;
        __half h[C];
#pragma unroll
        for (int c = 0; c < C; ++c) h[c] = __float2half(src[(size_t)c * HW]);
        float4* dst = reinterpret_cast<float4*>(imgH + ((size_t)bl * HW + pix) * C);
        *dst = *reinterpret_cast<float4*>(h);
    }
}

// ---------------------------------------------------------------------------
// Per-sample geometry (lean, R12-proven).
// x wrap: remainder(v,2) = v - 2*floor(v*0.5) — bit-identical to the
// reference's jnp.remainder for our value range (intermediates exact,
// same single final rounding op). Validity (UNCLAMPED floored coords,
// matching the reference) folded into wx/wy before the weight products.
// x0f in [-1,47] automatically (v in [0,2)); y0f UNBOUNDED -> double-sided
// clamps (one-sided clamping caused R5's 0*NaN poisoning — never again).
// ---------------------------------------------------------------------------
struct TapPack {
    float w00, w10, w01, w11;
    int o00, o10, o01, o11;    // element offsets of the 4 clamped taps
};

__device__ __forceinline__ TapPack geom(float base_gx_p1, float base_gy,
                                        float relx, float rely) {
    float v = base_gx_p1 + relx;
    v = __builtin_fmaf(-2.0f, floorf(v * 0.5f), v);       // remainder(v,2) in [0,2)

    float ix = __builtin_fmaf(v, 24.0f, -0.5f);           // [-0.5, 47.5)
    float gy = base_gy + rely;
    float iy = __builtin_fmaf(gy, 24.0f, 23.5f);

    float x0f = floorf(ix), y0f = floorf(iy);
    float wx1 = ix - x0f,   wy1 = iy - y0f;
    float wx0 = 1.0f - wx1, wy0 = 1.0f - wy1;

    // validity folded (x0f <= 47 and x0f >= -1 hold automatically)
    wx0 = (x0f >= 0.0f)                      ? wx0 : 0.0f;
    wx1 = (x0f <= 46.0f)                     ? wx1 : 0.0f;
    wy0 = (y0f >= 0.0f  && y0f <= 47.0f)     ? wy0 : 0.0f;
    wy1 = (y0f >= -1.0f && y0f <= 46.0f)     ? wy1 : 0.0f;

    // clamped integer taps (y unbounded -> double-sided)
    int x0 = (int)fmaxf(x0f, 0.0f);
    int x1 = (int)fminf(x0f + 1.0f, 47.0f);
    int y0 = (int)fminf(fmaxf(y0f,        0.0f), 47.0f);
    int y1 = (int)fminf(fmaxf(y0f + 1.0f, 0.0f), 47.0f);

    TapPack t;
    t.w00 = wx0 * wy0; t.w10 = wx1 * wy0;
    t.w01 = wx0 * wy1; t.w11 = wx1 * wy1;
    int y0b = y0 * (W * C), y1b = y1 * (W * C);
    t.o00 = y0b + x0 * C;  t.o10 = y0b + x1 * C;
    t.o01 = y1b + x0 * C;  t.o11 = y1b + x1 * C;
    return t;
}

// ---------------------------------------------------------------------------
// f32 += f16 * f32 via v_fma_mix_f32 (no separate cvt): lo and hi half of
// one 32-bit word of packed f16 into two accumulators.
// ---------------------------------------------------------------------------
__device__ __forceinline__ void fma_mix2(float& alo, float& ahi, uint32_t hw, float w) {
    asm("v_fma_mix_f32 %0, %2, %3, %0 op_sel:[0,0,0] op_sel_hi:[1,0,0]\n\t"
        "v_fma_mix_f32 %1, %2, %3, %1 op_sel:[1,0,0] op_sel_hi:[1,0,0]"
        : "+v"(alo), "+v"(ahi)
        : "v"(hw), "v"(w));
}

// ---------------------------------------------------------------------------
// Stage one fp16 frame (2304 records x 16B = 36.9 KB) global -> LDS, linear.
// ---------------------------------------------------------------------------
#if defined(__has_builtin)
#if __has_builtin(__builtin_amdgcn_global_load_lds)
#define HAVE_GLD_LDS 1
#endif
#endif

__device__ __forceinline__ void stage_frame(const __half* __restrict__ gsrc,
                                            __half* lds_base, int tid) {
#ifdef HAVE_GLD_LDS
#pragma unroll
    for (int i = 0; i < 9; ++i) {
        const int r = i * 256 + tid;
        __builtin_amdgcn_global_load_lds(
            (const __attribute__((address_space(1))) void*)(gsrc + (size_t)r * C),
            (__attribute__((address_space(3))) void*)(lds_base + (size_t)r * C),
            16, 0, 0);
    }
#else
#pragma unroll
    for (int i = 0; i < 9; ++i) {
        const int r = i * 256 + tid;
        float4 v = *reinterpret_cast<const float4*>(gsrc + (size_t)r * C);
        *reinterpret_cast<float4*>(lds_base + (size_t)r * C) = v;
    }
#endif
}

// ---------------------------------------------------------------------------
// Gather 4 taps from the LDS frame, accumulate 8 channels via fma_mix.
// Clamped offsets + zeroed weights (0 * finite LDS data — no NaN possible).
// ---------------------------------------------------------------------------
__device__ __forceinline__ void gather_mix(const __half* fb, const TapPack& t,
                                           float acc[C]) {
    float4 r00 = *reinterpret_cast<const float4*>(fb + t.o00);
    float4 r10 = *reinterpret_cast<const float4*>(fb + t.o10);
    float4 r01 = *reinterpret_cast<const float4*>(fb + t.o01);
    float4 r11 = *reinterpret_cast<const float4*>(fb + t.o11);
    auto mixtap = [&](const float4& raw, float w) {
        const uint32_t* u = reinterpret_cast<const uint32_t*>(&raw);
        fma_mix2(acc[0], acc[1], u[0], w);
        fma_mix2(acc[2], acc[3], u[1], w);
        fma_mix2(acc[4], acc[5], u[2], w);
        fma_mix2(acc[6], acc[7], u[3], w);
    };
    mixtap(r00, t.w00); mixtap(r10, t.w10);
    mixtap(r01, t.w01); mixtap(r11, t.w11);
}

// ---------------------------------------------------------------------------
// Main kernel: T=12 t's per staged frame, k split into P=7 parity classes.
// Proven R7/R10/R12 loop shape: double-buffered global_load_lds staging, one
// barrier per k, 73.7 KB LDS -> 2 blocks/CU (co-resident blocks hide each
// other's barrier drains).
// R13 lesson: T16 regressed (partial traffic + register pressure beat the
// staging saving) -> stay at T12. R14 change: P=6 -> 7 for CU-fill — grid
// (9,4,14) = 504 blocks ~= 2/CU on 98% of CUs (R12's 432 left 80 CUs idle
// half the makespan), and per-block iterations drop 8 -> 7.
// t-set(g) = {8m+g, 8m+7-g}, m=0..5, g in 0..3: uniform 294 samples/pixel
// across the 7 par classes (42/thread/block); kmax = 47-g.
// acc[12][8] = 96 VGPR (no spill; launch_bounds(256,2)).
// par==0 writes out (fp32); par p>0 writes fp16 partial p-1; reduce sums.
// ---------------------------------------------------------------------------
constexpr int TT = 12;
constexpr int P  = 7;

__global__ __launch_bounds__(256, 2) void scan_kernel(const float* __restrict__ cum2,
                                                      const __half* __restrict__ imgH,
                                                      float* __restrict__ out,
                                                      __half* __restrict__ part) {
    const int tid  = threadIdx.x;
    const int pix0 = blockIdx.x * TPB;
    const int pix  = pix0 + tid;
    const int g    = blockIdx.y;
    const int par  = blockIdx.z % P;
    const int b    = blockIdx.z / P;

    int tj[TT];
#pragma unroll
    for (int m = 0; m < TT / 2; ++m) {
        tj[2 * m]     = 8 * m + g;
        tj[2 * m + 1] = 8 * m + 7 - g;
    }
    const int kmax = 47 - g;

    const int w = pix % W;
    const int h = pix / W;
    const float base_gx_p1 = (2 * w + 1) * (1.0f / W);
    const float base_gy    = (2 * h + 1) * (1.0f / H) - 1.0f;

    const float* cb = cum2 + ((size_t)b * L * HW + pix) * 2;
    float ctx[TT], cty[TT];
#pragma unroll
    for (int j = 0; j < TT; ++j) {
        float2 c = *reinterpret_cast<const float2*>(cb + (size_t)tj[j] * HW * 2);
        ctx[j] = c.x; cty[j] = c.y;
    }

    float acc[TT][C];
#pragma unroll
    for (int j = 0; j < TT; ++j)
#pragma unroll
        for (int c = 0; c < C; ++c) acc[j][c] = 0.0f;

    // 73.7 KB: two fp16 frame buffers (epilogue reuses as fp32 [48][256])
    __shared__ __align__(16) unsigned char smem[2 * HW * C * 2];
    __half* fr0 = reinterpret_cast<__half*>(smem);
    __half* fr1 = reinterpret_cast<__half*>(smem + HW * C * 2);

    const __half* gb = imgH + (size_t)b * L * HW * C;

    stage_frame(gb + (size_t)par * HW * C, fr0, tid);       // frame k=par
    float2 ck = *reinterpret_cast<const float2*>(cb + (size_t)par * HW * 2);
    __syncthreads();                                        // staging visible

    int cur = 0;
    for (int k = par; k <= kmax; k += P) {
        __half* nb = cur ? fr0 : fr1;
        const __half* fb = cur ? fr1 : fr0;
        if (k + P <= kmax)
            stage_frame(gb + (size_t)(k + P) * HW * C, nb, tid);
        float2 ckn = ck;
        if (k + P <= kmax)
            ckn = *reinterpret_cast<const float2*>(cb + (size_t)(k + P) * HW * 2);

#pragma unroll
        for (int j = 0; j < TT; ++j) {
            if (tj[j] >= k) {   // block-uniform guard
                TapPack t = geom(base_gx_p1, base_gy, ctx[j] - ck.x, cty[j] - ck.y);
                gather_mix(fb, t, acc[j]);
            }
        }

        ck = ckn;
        __syncthreads();    // gathers done + next staging landed -> safe swap
        cur ^= 1;
    }

    // ---- epilogue: transpose acc through LDS, 2 rounds of 48 planes ----
    constexpr int NPLANES = TT * C;                     // 96
    float* accT = reinterpret_cast<float*>(smem);       // [48][256] = 48 KB
    const int lane = tid & 63;
    const int wv   = tid >> 6;

#pragma unroll
    for (int rd = 0; rd < 2; ++rd) {
        __syncthreads();
#pragma unroll
        for (int j = 0; j < TT; ++j)
#pragma unroll
            for (int c = 0; c < C; ++c) {
                int pl = j * C + c;
                if (pl / 48 == rd)
                    accT[(pl % 48) * TPB + tid] = acc[j][c];
            }
        __syncthreads();

#pragma unroll
        for (int rr = 0; rr < 12; ++rr) {               // 48 planes / 4 waves
            int pl_l = wv + 4 * rr;
            int pl_g = rd * 48 + pl_l;
            if (pl_g < NPLANES) {
                int j = pl_g >> 3, c = pl_g & 7;
                float4 v = *reinterpret_cast<float4*>(&accT[pl_l * TPB + lane * 4]);
                size_t off = ((size_t)(b * L + tj[j]) * C + c) * HW + pix0 + lane * 4;
                if (par == 0) {
                    *reinterpret_cast<float4*>(out + off) = v;
                } else {
                    __half hb[4];
                    hb[0] = __float2half(v.x); hb[1] = __float2half(v.y);
                    hb[2] = __float2half(v.z); hb[3] = __float2half(v.w);
                    *reinterpret_cast<float2*>(part + (size_t)(par - 1) * OUT_ELEMS + off) =
                        *reinterpret_cast<float2*>(hb);
                }
            }
        }
    }
}

// ---------------------------------------------------------------------------
// Reduce: out += sum of NPART fp16 partials, fixed order -> deterministic.
// ---------------------------------------------------------------------------
template <int NPART>
__global__ void reduce_kernel(float* __restrict__ out, const __half* __restrict__ part) {
    int i = blockIdx.x * blockDim.x + threadIdx.x;
    constexpr int N4 = OUT_ELEMS / 4;
    if (i < N4) {
        float4 a = reinterpret_cast<float4*>(out)[i];
#pragma unroll
        for (int p = 0; p < NPART; ++p) {
            const __half2* hp = reinterpret_cast<const __half2*>(
                part + (size_t)p * OUT_ELEMS + 4 * (size_t)i);
            float2 f01 = __half22float2(hp[0]);
            float2 f23 = __half22float2(hp[1]);
            a.x += f01.x; a.y += f01.y; a.z += f23.x; a.w += f23.y;
        }
        reinterpret_cast<float4*>(out)[i] = a;
    }
}

// ---------------------------------------------------------------------------
extern "C" void kernel_launch(void* const* d_in, const int* in_sizes, int n_in,
                              void* d_out, int out_size, void* d_ws, size_t ws_size,
                              hipStream_t stream) {
    const float* flows  = (const float*)d_in[0];   // (B, L, 2, H, W) fp32
    const float* images = (const float*)d_in[1];   // (B, L, C, H, W) fp32
    float* out = (float*)d_out;                    // (B, L, C, H, W) fp32

    const size_t cum_elems  = (size_t)B * L * 2 * HW;     // 442,368 f32
    const size_t imgH_elems = (size_t)B * L * HW * C;     // 1,769,472 f16

    float*  cum2 = (float*)d_ws;
    __half* imgH = (__half*)(cum2 + cum_elems);
    __half* part = imgH + imgH_elems;                     // 6 fp16 partials (21.2 MB)

    prep_kernel<<<CUM_BLOCKS + CONV_BLOCKS, 256, 0, stream>>>(flows, images, cum2, imgH);

    dim3 grid(CHUNKS, 4, 2 * P);                          // (9, 4, 14) = 504 blocks
    scan_kernel<<<grid, 256, 0, stream>>>(cum2, imgH, out, part);

    constexpr int N4 = OUT_ELEMS / 4;
    reduce_kernel<P - 1><<<(N4 + 255) / 256, 256, 0, stream>>>(out, part);
}